// Round 2
// baseline (331.587 us; speedup 1.0000x reference)
//
#include <hip/hip_runtime.h>
#include <hip/hip_bf16.h>

typedef __attribute__((ext_vector_type(8))) short short8;
typedef __attribute__((ext_vector_type(4))) float floatx4;

#define N_ROWS 8192
#define C_DIM  128
#define CH     8
#define CHUNK  (N_ROWS / CH)               /* 1024 cols per block */
#define KSCALE 14.426950408889634f         /* 10 * log2(e) */
#define LN2    0.6931471805599453f

__device__ __forceinline__ unsigned short f2bf(float f) {
    union { float f; unsigned int u; } x; x.f = f;
    unsigned int r = x.u + 0x7FFFu + ((x.u >> 16) & 1u);
    return (unsigned short)(r >> 16);
}
__device__ __forceinline__ float bf2f(unsigned short s) {
    union { unsigned int u; float f; } x; x.u = ((unsigned int)s) << 16;
    return x.f;
}

// One wave per row: L2-normalize 128 f32 -> 128 bf16
__global__ __launch_bounds__(256) void norm_kernel(
    const float* __restrict__ img, const float* __restrict__ mol,
    unsigned short* __restrict__ W)
{
    int wave = threadIdx.x >> 6, lane = threadIdx.x & 63;
    int row = blockIdx.x * 4 + wave;               // 0..16383
    const float* src = (row < N_ROWS) ? (img + (size_t)row * C_DIM)
                                      : (mol + (size_t)(row - N_ROWS) * C_DIM);
    float2 v = *reinterpret_cast<const float2*>(src + lane * 2);
    float ss = v.x * v.x + v.y * v.y;
    #pragma unroll
    for (int m = 1; m < 64; m <<= 1) ss += __shfl_xor(ss, m);
    float inv = rsqrtf(ss);
    unsigned short* dst = W + (size_t)row * C_DIM;
    dst[lane * 2]     = f2bf(v.x * inv);
    dst[lane * 2 + 1] = f2bf(v.y * inv);
}

__device__ __forceinline__ void load_btile(short8 (&bf)[2][4],
    const unsigned short* __restrict__ Y, int jb, int l15, int lg)
{
    #pragma unroll
    for (int n = 0; n < 2; ++n)
        #pragma unroll
        for (int k = 0; k < 4; ++k)
            bf[n][k] = *reinterpret_cast<const short8*>(
                Y + (size_t)(jb + n * 16 + l15) * C_DIM + k * 32 + lg * 8);
}

__device__ __forceinline__ void compute_tile(
    const short8 (&af)[2][4], const short8 (&bf)[2][4], float (&se)[2][4])
{
    #pragma unroll
    for (int m = 0; m < 2; ++m)
        #pragma unroll
        for (int n = 0; n < 2; ++n) {
            floatx4 acc = {0.f, 0.f, 0.f, 0.f};
            #pragma unroll
            for (int k = 0; k < 4; ++k)
                acc = __builtin_amdgcn_mfma_f32_16x16x32_bf16(
                          af[m][k], bf[n][k], acc, 0, 0, 0);
            #pragma unroll
            for (int r = 0; r < 4; ++r)
                se[m][r] += __builtin_amdgcn_exp2f(acc[r] * KSCALE - KSCALE);
        }
}

// grid: (64 row-blocks, CH col-chunks, 4 passes). No diag handling here;
// partial sum-exp (diag included) accumulated to SE[pass][row].
__global__ __launch_bounds__(256) void pass_kernel(
    const unsigned short* __restrict__ W, float* __restrict__ SE)
{
    int pass = blockIdx.z;
    const unsigned short* X = (pass < 2) ? W : W + (size_t)N_ROWS * C_DIM;
    const unsigned short* Y = (pass == 1 || pass == 2)
                                ? W + (size_t)N_ROWS * C_DIM : W;
    int lane = threadIdx.x & 63, wave = threadIdx.x >> 6;
    int l15 = lane & 15, lg = lane >> 4;
    int rbase = blockIdx.x * 128 + wave * 32;
    int cstart = blockIdx.y * CHUNK, cend = cstart + CHUNK;

    short8 af[2][4];
    #pragma unroll
    for (int m = 0; m < 2; ++m)
        #pragma unroll
        for (int k = 0; k < 4; ++k)
            af[m][k] = *reinterpret_cast<const short8*>(
                X + (size_t)(rbase + m * 16 + l15) * C_DIM + k * 32 + lg * 8);

    float se[2][4] = {{0.f,0.f,0.f,0.f},{0.f,0.f,0.f,0.f}};

    short8 bA[2][4], bB[2][4];
    load_btile(bA, Y, cstart, l15, lg);
    for (int jb = cstart; jb < cend; jb += 64) {
        load_btile(bB, Y, jb + 32, l15, lg);
        compute_tile(af, bA, se);
        int nxt = (jb + 64 < cend) ? jb + 64 : cstart;
        load_btile(bA, Y, nxt, l15, lg);
        compute_tile(af, bB, se);
    }

    float* SEp = SE + (size_t)pass * N_ROWS;
    #pragma unroll
    for (int m = 0; m < 2; ++m)
        #pragma unroll
        for (int r = 0; r < 4; ++r) {
            float s = se[m][r];
            s += __shfl_xor(s, 1);
            s += __shfl_xor(s, 2);
            s += __shfl_xor(s, 4);
            s += __shfl_xor(s, 8);
            if (l15 == 0)
                atomicAdd(&SEp[rbase + m * 16 + lg * 4 + r], s);
        }
}

// One wave per row: recompute diag dots, mask, lse, accumulate loss.
__global__ __launch_bounds__(256) void finalize_kernel(
    const unsigned short* __restrict__ W, const float* __restrict__ SE,
    float* __restrict__ out)
{
    __shared__ float partial[4];
    int lane = threadIdx.x & 63, wave = threadIdx.x >> 6;
    int row = blockIdx.x * 4 + wave;
    const unsigned short* a = W + (size_t)row * C_DIM;
    const unsigned short* b = W + (size_t)(N_ROWS + row) * C_DIM;
    float a0 = bf2f(a[lane * 2]), a1 = bf2f(a[lane * 2 + 1]);
    float b0 = bf2f(b[lane * 2]), b1 = bf2f(b[lane * 2 + 1]);
    float d00 = a0 * a0 + a1 * a1;
    float d01 = a0 * b0 + a1 * b1;
    float d11 = b0 * b0 + b1 * b1;
    #pragma unroll
    for (int m = 1; m < 64; m <<= 1) {
        d00 += __shfl_xor(d00, m);
        d01 += __shfl_xor(d01, m);
        d11 += __shfl_xor(d11, m);
    }
    if (lane == 0) {
        float s0 = SE[0 * N_ROWS + row] - __builtin_amdgcn_exp2f(KSCALE * (d00 - 1.f));
        float s1 = SE[1 * N_ROWS + row] - __builtin_amdgcn_exp2f(KSCALE * (d01 - 1.f));
        float s2 = SE[2 * N_ROWS + row] - __builtin_amdgcn_exp2f(KSCALE * (d11 - 1.f));
        float s3 = SE[3 * N_ROWS + row] - __builtin_amdgcn_exp2f(KSCALE * (d01 - 1.f));
        float l0 = LN2 * __builtin_amdgcn_logf(s0) + 10.f;
        float l1 = LN2 * __builtin_amdgcn_logf(s1) + 10.f;
        float l2 = LN2 * __builtin_amdgcn_logf(s2) + 10.f;
        float l3 = LN2 * __builtin_amdgcn_logf(s3) + 10.f;
        partial[wave] = -10.f * d01 + 0.5f * (l0 + l1 + l2 + l3);
    }
    __syncthreads();
    if (threadIdx.x == 0)
        atomicAdd(out, (partial[0] + partial[1] + partial[2] + partial[3])
                         * (1.0f / N_ROWS));
}

extern "C" void kernel_launch(void* const* d_in, const int* in_sizes, int n_in,
                              void* d_out, int out_size, void* d_ws, size_t ws_size,
                              hipStream_t stream)
{
    const float* img = (const float*)d_in[0];
    const float* mol = (const float*)d_in[1];
    float* out = (float*)d_out;
    unsigned short* W = (unsigned short*)d_ws;               // 4 MB bf16 A|B
    float* SE = (float*)((char*)d_ws + (size_t)2 * N_ROWS * C_DIM * 2); // 128 KB

    hipMemsetAsync(d_out, 0, sizeof(float), stream);
    hipMemsetAsync(SE, 0, (size_t)4 * N_ROWS * sizeof(float), stream);
    norm_kernel<<<dim3(N_ROWS * 2 / 4), 256, 0, stream>>>(img, mol, W);
    pass_kernel<<<dim3(N_ROWS / 128, CH, 4), 256, 0, stream>>>(W, SE);
    finalize_kernel<<<dim3(N_ROWS / 4), 256, 0, stream>>>(W, SE, out);
}

// Round 4
// 171.316 us; speedup vs baseline: 1.9355x; 1.9355x over previous
//
#include <hip/hip_runtime.h>
#include <hip/hip_bf16.h>

typedef __attribute__((ext_vector_type(8))) short short8;
typedef __attribute__((ext_vector_type(4))) float floatx4;

#define N_ROWS 8192
#define C_DIM  128
#define CH     8
#define CHUNK  (N_ROWS / CH)               /* 1024 cols per block */
#define NIT    (CHUNK / 64)                /* 16 col-tiles of 64 */
#define KSCALE 14.426950408889634f         /* 10 * log2(e) */
#define LN2    0.6931471805599453f

__device__ __forceinline__ unsigned int pack_bf16x2(float x, float y) {
    union { float f; unsigned int u; } a, b;
    a.f = x; b.f = y;
    unsigned int ra = a.u + 0x7FFFu + ((a.u >> 16) & 1u);
    unsigned int rb = b.u + 0x7FFFu + ((b.u >> 16) & 1u);
    return (ra >> 16) | ((rb >> 16) << 16);
}
__device__ __forceinline__ float bf2f(unsigned short s) {
    union { unsigned int u; float f; } x; x.u = ((unsigned int)s) << 16;
    return x.f;
}

// One wave per row: L2-normalize 128 f32 -> 128 bf16 (packed 4B store/lane)
__global__ __launch_bounds__(256) void norm_kernel(
    const float* __restrict__ img, const float* __restrict__ mol,
    unsigned short* __restrict__ W)
{
    int wave = threadIdx.x >> 6, lane = threadIdx.x & 63;
    int row = blockIdx.x * 4 + wave;               // 0..16383
    const float* src = (row < N_ROWS) ? (img + (size_t)row * C_DIM)
                                      : (mol + (size_t)(row - N_ROWS) * C_DIM);
    float2 v = *reinterpret_cast<const float2*>(src + lane * 2);
    float ss = v.x * v.x + v.y * v.y;
    #pragma unroll
    for (int m = 1; m < 64; m <<= 1) ss += __shfl_xor(ss, m);
    float inv = rsqrtf(ss);
    ((unsigned int*)(W + (size_t)row * C_DIM))[lane] =
        pack_bf16x2(v.x * inv, v.y * inv);
}

// grid: (64 row-blocks, CH col-chunks, 4 passes). Partial sum-exp -> SE.
// B-tiles (64 rows x 128 bf16) staged to LDS via global_load_lds,
// double-buffered, counted vmcnt. XOR swizzle ((r&7) on 16B slot) applied
// on the GLOBAL source (LDS dest linear, per m104/m173) and on ds_read.
__global__ __launch_bounds__(256) void pass_kernel(
    const unsigned short* __restrict__ W, float* __restrict__ SE)
{
    __shared__ unsigned short buf[2][64][128];     // 2 x 16 KB
    int pass = blockIdx.z;
    const unsigned short* X = (pass < 2) ? W : W + (size_t)N_ROWS * C_DIM;
    const unsigned short* Y = (pass == 1 || pass == 2)
                                ? W + (size_t)N_ROWS * C_DIM : W;
    int lane = threadIdx.x & 63, wave = threadIdx.x >> 6;
    int l15 = lane & 15, lg = lane >> 4;
    int rbase = blockIdx.x * 128 + wave * 32;
    int cstart = blockIdx.y * CHUNK;

    // A fragments in registers for the whole sweep (once per block)
    short8 af[2][4];
    #pragma unroll
    for (int m = 0; m < 2; ++m)
        #pragma unroll
        for (int k = 0; k < 4; ++k)
            af[m][k] = *reinterpret_cast<const short8*>(
                X + (size_t)(rbase + m * 16 + l15) * C_DIM + k * 32 + lg * 8);

    // per-wave staging: 4 gload_lds insts, each 1KB contiguous LDS
    auto stage = [&](int bsel, int jb) {
        #pragma unroll
        for (int i = 0; i < 4; ++i) {
            int c = i * 4 + wave;                  // 1KB chunk 0..15
            int r = c * 4 + lg;                    // tile row 0..63
            int s = l15 ^ (r & 7);                 // pre-swizzled 16B slot
            const void* gsrc = (const char*)Y + (size_t)(jb + r) * 256 + s * 16;
            void* ldst = (char*)&buf[bsel][0][0] + c * 1024;
            __builtin_amdgcn_global_load_lds(
                (const __attribute__((address_space(1))) unsigned int*)gsrc,
                (__attribute__((address_space(3))) unsigned int*)ldst,
                16, 0, 0);
        }
    };

    float se[2][4] = {{0.f,0.f,0.f,0.f},{0.f,0.f,0.f,0.f}};

    stage(0, cstart);
    int cur = 0;
    for (int it = 0; it < NIT; ++it) {
        if (it + 1 < NIT) {
            stage(cur ^ 1, cstart + (it + 1) * 64);
            asm volatile("s_waitcnt vmcnt(4)" ::: "memory");  // cur's 4 landed
        } else {
            asm volatile("s_waitcnt vmcnt(0)" ::: "memory");
        }
        __builtin_amdgcn_s_barrier();
        asm volatile("" ::: "memory");             // no ds_read hoist above bar

        #pragma unroll
        for (int n = 0; n < 4; ++n) {              // all 64 staged rows
            short8 bk[4];
            #pragma unroll
            for (int k = 0; k < 4; ++k) {
                int row = n * 16 + l15;
                int s = (k * 4 + lg) ^ (l15 & 7);  // un-swizzle on read
                bk[k] = *reinterpret_cast<const short8*>(
                    (const char*)&buf[cur][0][0] + row * 256 + s * 16);
            }
            #pragma unroll
            for (int m = 0; m < 2; ++m) {
                floatx4 acc = {0.f, 0.f, 0.f, 0.f};
                #pragma unroll
                for (int k = 0; k < 4; ++k)
                    acc = __builtin_amdgcn_mfma_f32_16x16x32_bf16(
                              af[m][k], bk[k], acc, 0, 0, 0);
                #pragma unroll
                for (int r = 0; r < 4; ++r)
                    se[m][r] += __builtin_amdgcn_exp2f(acc[r] * KSCALE - KSCALE);
            }
        }
        asm volatile("s_waitcnt lgkmcnt(0)" ::: "memory");  // ds_reads done
        __builtin_amdgcn_sched_barrier(0);
        __builtin_amdgcn_s_barrier();              // safe to overwrite buf[cur]
        cur ^= 1;
    }

    float* SEp = SE + (size_t)pass * N_ROWS;
    #pragma unroll
    for (int m = 0; m < 2; ++m)
        #pragma unroll
        for (int r = 0; r < 4; ++r) {
            float s = se[m][r];
            s += __shfl_xor(s, 1);
            s += __shfl_xor(s, 2);
            s += __shfl_xor(s, 4);
            s += __shfl_xor(s, 8);
            if (l15 == 0)
                atomicAdd(&SEp[rbase + m * 16 + lg * 4 + r], s);
        }
}

// One wave per row: recompute diag dots, mask, lse, accumulate loss.
__global__ __launch_bounds__(256) void finalize_kernel(
    const unsigned short* __restrict__ W, const float* __restrict__ SE,
    float* __restrict__ out)
{
    __shared__ float partial[4];
    int lane = threadIdx.x & 63, wave = threadIdx.x >> 6;
    int row = blockIdx.x * 4 + wave;
    const unsigned short* a = W + (size_t)row * C_DIM;
    const unsigned short* b = W + (size_t)(N_ROWS + row) * C_DIM;
    float a0 = bf2f(a[lane * 2]), a1 = bf2f(a[lane * 2 + 1]);
    float b0 = bf2f(b[lane * 2]), b1 = bf2f(b[lane * 2 + 1]);
    float d00 = a0 * a0 + a1 * a1;
    float d01 = a0 * b0 + a1 * b1;
    float d11 = b0 * b0 + b1 * b1;
    #pragma unroll
    for (int m = 1; m < 64; m <<= 1) {
        d00 += __shfl_xor(d00, m);
        d01 += __shfl_xor(d01, m);
        d11 += __shfl_xor(d11, m);
    }
    if (lane == 0) {
        float s0 = SE[0 * N_ROWS + row] - __builtin_amdgcn_exp2f(KSCALE * (d00 - 1.f));
        float s1 = SE[1 * N_ROWS + row] - __builtin_amdgcn_exp2f(KSCALE * (d01 - 1.f));
        float s2 = SE[2 * N_ROWS + row] - __builtin_amdgcn_exp2f(KSCALE * (d11 - 1.f));
        float s3 = SE[3 * N_ROWS + row] - __builtin_amdgcn_exp2f(KSCALE * (d01 - 1.f));
        float l0 = LN2 * __builtin_amdgcn_logf(s0) + 10.f;
        float l1 = LN2 * __builtin_amdgcn_logf(s1) + 10.f;
        float l2 = LN2 * __builtin_amdgcn_logf(s2) + 10.f;
        float l3 = LN2 * __builtin_amdgcn_logf(s3) + 10.f;
        partial[wave] = -10.f * d01 + 0.5f * (l0 + l1 + l2 + l3);
    }
    __syncthreads();
    if (threadIdx.x == 0)
        atomicAdd(out, (partial[0] + partial[1] + partial[2] + partial[3])
                         * (1.0f / N_ROWS));
}

extern "C" void kernel_launch(void* const* d_in, const int* in_sizes, int n_in,
                              void* d_out, int out_size, void* d_ws, size_t ws_size,
                              hipStream_t stream)
{
    const float* img = (const float*)d_in[0];
    const float* mol = (const float*)d_in[1];
    float* out = (float*)d_out;
    unsigned short* W = (unsigned short*)d_ws;               // 4 MB bf16 A|B
    float* SE = (float*)((char*)d_ws + (size_t)2 * N_ROWS * C_DIM * 2); // 128 KB

    hipMemsetAsync(d_out, 0, sizeof(float), stream);
    hipMemsetAsync(SE, 0, (size_t)4 * N_ROWS * sizeof(float), stream);
    norm_kernel<<<dim3(N_ROWS * 2 / 4), 256, 0, stream>>>(img, mol, W);
    pass_kernel<<<dim3(N_ROWS / 128, CH, 4), 256, 0, stream>>>(W, SE);
    finalize_kernel<<<dim3(N_ROWS / 4), 256, 0, stream>>>(W, SE, out);
}

// Round 5
// 153.370 us; speedup vs baseline: 2.1620x; 1.1170x over previous
//
#include <hip/hip_runtime.h>
#include <hip/hip_bf16.h>

typedef __attribute__((ext_vector_type(8))) short short8;
typedef __attribute__((ext_vector_type(4))) float floatx4;

#define N_ROWS 8192
#define C_DIM  128
#define CHUNK  512                         /* cols per block */
#define NIT    (CHUNK / 64)                /* 8 col-tiles of 64 */
#define KSCALE 14.426950408889634f         /* 10 * log2(e) */
#define LN2    0.6931471805599453f

__device__ __forceinline__ unsigned int pack_bf16x2(float x, float y) {
    union { float f; unsigned int u; } a, b;
    a.f = x; b.f = y;
    unsigned int ra = a.u + 0x7FFFu + ((a.u >> 16) & 1u);
    unsigned int rb = b.u + 0x7FFFu + ((b.u >> 16) & 1u);
    return (ra >> 16) | ((rb >> 16) << 16);
}
__device__ __forceinline__ float bf2f(unsigned short s) {
    union { unsigned int u; float f; } x; x.u = ((unsigned int)s) << 16;
    return x.f;
}

// One wave per row: L2-normalize 128 f32 -> 128 bf16. Also zero SE and out.
__global__ __launch_bounds__(256) void norm_kernel(
    const float* __restrict__ img, const float* __restrict__ mol,
    unsigned short* __restrict__ W, float* __restrict__ SE,
    float* __restrict__ out)
{
    if (blockIdx.x < 32) {                         // zero SE[4][8192]
        int t = blockIdx.x * 1024 + threadIdx.x;
        SE[t] = 0.f; SE[t + 256] = 0.f; SE[t + 512] = 0.f; SE[t + 768] = 0.f;
        if (blockIdx.x == 0 && threadIdx.x == 0) *out = 0.f;
    }
    int wave = threadIdx.x >> 6, lane = threadIdx.x & 63;
    int row = blockIdx.x * 4 + wave;               // 0..16383
    const float* src = (row < N_ROWS) ? (img + (size_t)row * C_DIM)
                                      : (mol + (size_t)(row - N_ROWS) * C_DIM);
    float2 v = *reinterpret_cast<const float2*>(src + lane * 2);
    float ss = v.x * v.x + v.y * v.y;
    #pragma unroll
    for (int m = 1; m < 64; m <<= 1) ss += __shfl_xor(ss, m);
    float inv = rsqrtf(ss);
    ((unsigned int*)(W + (size_t)row * C_DIM))[lane] =
        pack_bf16x2(v.x * inv, v.y * inv);
}

// Symmetric-aware pass. Block decode:
//   idx<1024        : AB full (64 rb x 16 ch), dual: rows->SE1, cols->SE3
//   idx<1024+544    : AA (diag supers single ->SE0, upper supers dual ->SE0)
//   else            : BB likewise ->SE2
// Each block: 128 rows x 512 cols. B-tiles (64x128) staged via
// global_load_lds, double-buffered, counted vmcnt, XOR-swizzled source.
__global__ __launch_bounds__(256) void pass_kernel(
    const unsigned short* __restrict__ W, float* __restrict__ SE)
{
    __shared__ unsigned short buf[2][64][128];     // 2 x 16 KB
    __shared__ float colbuf[CHUNK];                // 2 KB

    int idx = blockIdx.x;
    const unsigned short *X, *Y;
    float *rowSE, *colSE;
    bool dual;
    int rb, ch;
    if (idx < 1024) {
        rb = idx >> 4; ch = idx & 15;
        X = W; Y = W + (size_t)N_ROWS * C_DIM;
        rowSE = SE + 1 * N_ROWS; colSE = SE + 3 * N_ROWS; dual = true;
    } else {
        int j = idx - 1024;
        const unsigned short* M = (j < 544) ? W : W + (size_t)N_ROWS * C_DIM;
        float* S = (j < 544) ? SE : SE + 2 * N_ROWS;
        if (j >= 544) j -= 544;
        X = M; Y = M; rowSE = S; colSE = S;
        if (j < 64) { rb = j; ch = rb >> 2; dual = false; }
        else {
            int j2 = j - 64, p = j2 >> 2;
            int si = 0, cum = 15;
            while (p >= cum) { p -= cum; ++si; cum = 15 - si; }
            int sj = si + 1 + p;
            rb = si * 4 + (j2 & 3); ch = sj; dual = true;
        }
    }

    int lane = threadIdx.x & 63, wave = threadIdx.x >> 6;
    int l15 = lane & 15, lg = lane >> 4;
    int rbase = rb * 128 + wave * 32;
    int cstart = ch * CHUNK;

    // A fragments in registers for the whole sweep
    short8 af[2][4];
    #pragma unroll
    for (int m = 0; m < 2; ++m)
        #pragma unroll
        for (int k = 0; k < 4; ++k)
            af[m][k] = *reinterpret_cast<const short8*>(
                X + (size_t)(rbase + m * 16 + l15) * C_DIM + k * 32 + lg * 8);

    auto stage = [&](int bsel, int jb) {
        #pragma unroll
        for (int i = 0; i < 4; ++i) {
            int c = i * 4 + wave;                  // 1KB chunk 0..15
            int r = c * 4 + lg;                    // tile row 0..63
            int s = l15 ^ (r & 7);                 // pre-swizzled 16B slot
            const void* gsrc = (const char*)Y + (size_t)(cstart + jb + r) * 256 + s * 16;
            void* ldst = (char*)&buf[bsel][0][0] + c * 1024;
            __builtin_amdgcn_global_load_lds(
                (const __attribute__((address_space(1))) unsigned int*)gsrc,
                (__attribute__((address_space(3))) unsigned int*)ldst,
                16, 0, 0);
        }
    };

    for (int c = threadIdx.x; c < CHUNK; c += 256) colbuf[c] = 0.f;

    float se[2][4] = {{0.f,0.f,0.f,0.f},{0.f,0.f,0.f,0.f}};

    stage(0, 0);
    int cur = 0;
    for (int it = 0; it < NIT; ++it) {
        if (it + 1 < NIT) {
            stage(cur ^ 1, (it + 1) * 64);
            asm volatile("s_waitcnt vmcnt(4)" ::: "memory");
        } else {
            asm volatile("s_waitcnt vmcnt(0)" ::: "memory");
        }
        __builtin_amdgcn_s_barrier();
        asm volatile("" ::: "memory");

        float ce[4] = {0.f, 0.f, 0.f, 0.f};
        #pragma unroll
        for (int n = 0; n < 4; ++n) {              // all 64 staged rows
            short8 bk[4];
            #pragma unroll
            for (int k = 0; k < 4; ++k) {
                int row = n * 16 + l15;
                int s = (k * 4 + lg) ^ (l15 & 7);  // un-swizzle on read
                bk[k] = *reinterpret_cast<const short8*>(
                    (const char*)&buf[cur][0][0] + row * 256 + s * 16);
            }
            #pragma unroll
            for (int m = 0; m < 2; ++m) {
                floatx4 acc = {0.f, 0.f, 0.f, 0.f};
                #pragma unroll
                for (int k = 0; k < 4; ++k)
                    acc = __builtin_amdgcn_mfma_f32_16x16x32_bf16(
                              af[m][k], bk[k], acc, 0, 0, 0);
                #pragma unroll
                for (int r = 0; r < 4; ++r) {
                    float e = __builtin_amdgcn_exp2f(acc[r] * KSCALE - KSCALE);
                    se[m][r] += e;
                    ce[n] += e;
                }
            }
        }
        if (dual) {
            #pragma unroll
            for (int n = 0; n < 4; ++n) {
                float c2 = ce[n];
                c2 += __shfl_xor(c2, 16);
                c2 += __shfl_xor(c2, 32);
                if (lg == 0)
                    atomicAdd(&colbuf[it * 64 + n * 16 + l15], c2);
            }
        }
        asm volatile("s_waitcnt lgkmcnt(0)" ::: "memory");
        __builtin_amdgcn_sched_barrier(0);
        __builtin_amdgcn_s_barrier();
        cur ^= 1;
    }

    // row sums -> rowSE
    #pragma unroll
    for (int m = 0; m < 2; ++m)
        #pragma unroll
        for (int r = 0; r < 4; ++r) {
            float s = se[m][r];
            s += __shfl_xor(s, 1);
            s += __shfl_xor(s, 2);
            s += __shfl_xor(s, 4);
            s += __shfl_xor(s, 8);
            if (l15 == 0)
                atomicAdd(&rowSE[rbase + m * 16 + lg * 4 + r], s);
        }
    // col sums -> colSE (only dual blocks)
    __syncthreads();
    if (dual)
        for (int c = threadIdx.x; c < CHUNK; c += 256)
            atomicAdd(&colSE[cstart + c], colbuf[c]);
}

// One wave per row: recompute diag dots, mask, lse, accumulate loss.
__global__ __launch_bounds__(256) void finalize_kernel(
    const unsigned short* __restrict__ W, const float* __restrict__ SE,
    float* __restrict__ out)
{
    __shared__ float partial[4];
    int lane = threadIdx.x & 63, wave = threadIdx.x >> 6;
    int row = blockIdx.x * 4 + wave;
    const unsigned short* a = W + (size_t)row * C_DIM;
    const unsigned short* b = W + (size_t)(N_ROWS + row) * C_DIM;
    float a0 = bf2f(a[lane * 2]), a1 = bf2f(a[lane * 2 + 1]);
    float b0 = bf2f(b[lane * 2]), b1 = bf2f(b[lane * 2 + 1]);
    float d00 = a0 * a0 + a1 * a1;
    float d01 = a0 * b0 + a1 * b1;
    float d11 = b0 * b0 + b1 * b1;
    #pragma unroll
    for (int m = 1; m < 64; m <<= 1) {
        d00 += __shfl_xor(d00, m);
        d01 += __shfl_xor(d01, m);
        d11 += __shfl_xor(d11, m);
    }
    if (lane == 0) {
        float s0 = SE[0 * N_ROWS + row] - __builtin_amdgcn_exp2f(KSCALE * (d00 - 1.f));
        float s1 = SE[1 * N_ROWS + row] - __builtin_amdgcn_exp2f(KSCALE * (d01 - 1.f));
        float s2 = SE[2 * N_ROWS + row] - __builtin_amdgcn_exp2f(KSCALE * (d11 - 1.f));
        float s3 = SE[3 * N_ROWS + row] - __builtin_amdgcn_exp2f(KSCALE * (d01 - 1.f));
        float l0 = LN2 * __builtin_amdgcn_logf(s0) + 10.f;
        float l1 = LN2 * __builtin_amdgcn_logf(s1) + 10.f;
        float l2 = LN2 * __builtin_amdgcn_logf(s2) + 10.f;
        float l3 = LN2 * __builtin_amdgcn_logf(s3) + 10.f;
        partial[wave] = -10.f * d01 + 0.5f * (l0 + l1 + l2 + l3);
    }
    __syncthreads();
    if (threadIdx.x == 0)
        atomicAdd(out, (partial[0] + partial[1] + partial[2] + partial[3])
                         * (1.0f / N_ROWS));
}

extern "C" void kernel_launch(void* const* d_in, const int* in_sizes, int n_in,
                              void* d_out, int out_size, void* d_ws, size_t ws_size,
                              hipStream_t stream)
{
    const float* img = (const float*)d_in[0];
    const float* mol = (const float*)d_in[1];
    float* out = (float*)d_out;
    unsigned short* W = (unsigned short*)d_ws;               // 4 MB bf16 A|B
    float* SE = (float*)((char*)d_ws + (size_t)2 * N_ROWS * C_DIM * 2); // 128 KB

    norm_kernel<<<dim3(N_ROWS * 2 / 4), 256, 0, stream>>>(img, mol, W, SE, out);
    pass_kernel<<<dim3(1024 + 544 + 544), 256, 0, stream>>>(W, SE);
    finalize_kernel<<<dim3(N_ROWS / 4), 256, 0, stream>>>(W, SE, out);
}